// Round 14
// baseline (167.500 us; speedup 1.0000x reference)
//
#include <hip/hip_runtime.h>
#include <hip/hip_bf16.h>

using short8 = __attribute__((ext_vector_type(8))) short;
using f32x4  = __attribute__((ext_vector_type(4))) float;

#define MBATCH 16
#define NUMV   128
#define LEN    64
#define SZ     256

__device__ __forceinline__ unsigned short bfbits(float x) {
  union { float f; unsigned u; } c; c.f = x;
  return (unsigned short)((c.u + 0x8000u) >> 16);   // round-to-nearest
}

typedef const unsigned char __attribute__((address_space(1))) gu8;
typedef unsigned char __attribute__((address_space(3))) lu8;
__device__ __forceinline__ void gload_lds16(const void* g, void* l) {
  // dest = (wave-uniform l) + lane*16 ; src = per-lane g
  __builtin_amdgcn_global_load_lds((gu8*)g, (lu8*)l, 16, 0, 0);
}

// ---------------- prep 1: u[bn][s], v[bn][s] (layer-1 factorization) ----------------
__global__ void uv_prep(const float* __restrict__ in_, const float* __restrict__ W1,
                        const float* __restrict__ b1,
                        float* __restrict__ u, float* __restrict__ v) {
  int bn = blockIdx.x;
  int n  = bn & (NUMV - 1);
  int s  = threadIdx.x;                // 256 threads
  __shared__ float xs[LEN];
  if (s < LEN) xs[s] = in_[bn * LEN + s];
  __syncthreads();
  float fn = (float)n;
  float uu = fn * W1[64 * SZ + s];
  float vv = fn * W1[129 * SZ + s] + b1[s];
  for (int c = 0; c < LEN; ++c) {
    uu = fmaf(xs[c], W1[c * SZ + s], uu);
    vv = fmaf(xs[c], W1[(65 + c) * SZ + s], vv);
  }
  u[bn * SZ + s] = uu;
  v[bn * SZ + s] = vv;
}

// ---------------- prep 2: W2/W3/W4 -> bf16 A-fragments ----------------
// Step-major 16KB chunks (s = L*8+kb). Within a chunk: slot = (ch*4+q)^(ch&7),
// 16B at slot = Wt[ch][kb*32 + q*8 .. +7]. Linear == what global_load_lds stages.
__global__ void w_prep(const float* __restrict__ W2, const float* __restrict__ W3,
                       const float* __restrict__ W4, short* __restrict__ wlay) {
  int L = blockIdx.x >> 3, kb = blockIdx.x & 7;     // 24 blocks
  const float* W = (L == 0) ? W2 : (L == 1) ? W3 : W4;
  int c = threadIdx.x;                              // 256 threads = ch
  short* dst = wlay + (L * 8 + kb) * 8192;
  for (int qq = 0; qq < 4; ++qq) {
    short8 pk;
    for (int i = 0; i < 8; ++i)
      pk[i] = (short)bfbits(W[(kb * 32 + qq * 8 + i) * SZ + c]);
    int slot = (c * 4 + qq) ^ (c & 7);
    *reinterpret_cast<short8*>(dst + slot * 8) = pk;
  }
}

// ---------------- main fused kernel ----------------
// One WG per (b, a): 128 rows, 512 threads = 8 waves (wch 0..3, wrow 0..1).
// Wave tile 64ch x 64rows (acc[4][4] = 64 AGPR). Weights staged in LDS: 16KB/step
// shared by ALL 8 waves (weight requests/CU: 6.1 -> 1.5 MB), DMA'd ONE FULL STEP
// ahead into the other buffer; ONE barrier per step (its vmcnt-drain lands the DMA
// and closes the read-WAR on the current buffer). A-frag ds_read ~120cyc replaces
// the per-wave L2 round trip (~300-900cyc) that dominated R10-R13's step latency.
// LDS = 64K hbuf + 2x16K wbuf = 96KB -> 1 WG/CU; regs ~124 -> no spill.
__global__ __launch_bounds__(512, 2) void fused_mlp(
    const float* __restrict__ u, const float* __restrict__ v,
    const short* __restrict__ wlay,
    const float* __restrict__ b2, const float* __restrict__ b3, const float* __restrict__ b4,
    float* __restrict__ partial) {
  __shared__ __align__(16) short hbuf[128 * 256];   // 64 KB, byte ^= (row&7)<<4
  __shared__ __align__(16) short wbuf[2 * 8192];    // 2 x 16 KB step chunks

  int wg = blockIdx.x;
  int b = wg >> 7, a = wg & 127;
  int tid = threadIdx.x;
  int wave = tid >> 6, lane = tid & 63;
  int wch = wave & 3, wrow = wave >> 2;
  int l16 = lane & 15, q = lane >> 4;

  const char* wl0 = (const char*)wlay;

  // DMA step chunk s -> wbuf[buf]: 8 waves x 2KB each
  #define GLOAD(s, buf) { \
    const char* g = wl0 + (s) * 16384 + wave * 2048 + lane * 16; \
    char* d = (char*)wbuf + (buf) * 16384 + wave * 2048; \
    gload_lds16(g, d); \
    gload_lds16(g + 1024, d + 1024); }

  GLOAD(0, 0);            // step-0 chunk in flight under the whole h1 phase

  // ---- h1 = relu(u[b,j] + v[b,a]) -> bf16, swizzled row-major in LDS ----
  {
    const float4* ub = (const float4*)(u + (size_t)b * NUMV * SZ);
    const float4* vb = (const float4*)(v + ((size_t)b * NUMV + a) * SZ);
    #pragma unroll
    for (int it = 0; it < 16; ++it) {
      int flat = tid + it * 512;          // over 128 rows * 64 col-quads
      int jr = flat >> 6, c4 = flat & 63;
      float4 uu = ub[jr * 64 + c4];
      float4 vv = vb[c4];
      unsigned lo = (unsigned)bfbits(fmaxf(uu.x + vv.x, 0.f))
                  | ((unsigned)bfbits(fmaxf(uu.y + vv.y, 0.f)) << 16);
      unsigned hi = (unsigned)bfbits(fmaxf(uu.z + vv.z, 0.f))
                  | ((unsigned)bfbits(fmaxf(uu.w + vv.w, 0.f)) << 16);
      int byte = (jr * 512 + c4 * 8) ^ ((jr & 7) << 4);
      uint2 pk; pk.x = lo; pk.y = hi;
      *reinterpret_cast<uint2*>((char*)hbuf + byte) = pk;
    }
  }

  __syncthreads();        // h1 stores visible + step-0 DMA drained (vmcnt)

  int cur = 0;
  #pragma unroll
  for (int L = 0; L < 3; ++L) {
    const float* bb = (L == 0) ? b2 : (L == 1) ? b3 : b4;

    f32x4 acc[4][4];
    #pragma unroll
    for (int m = 0; m < 4; ++m)
      #pragma unroll
      for (int n = 0; n < 4; ++n)
        acc[m][n] = f32x4{0.f, 0.f, 0.f, 0.f};

    #pragma unroll
    for (int kb = 0; kb < 8; ++kb) {
      int s = L * 8 + kb;
      if (s < 23) GLOAD(s + 1, cur ^ 1);   // full-step-ahead prefetch

      const short* wb = wbuf + cur * 8192;
      short8 af[4], bfr[4];
      #pragma unroll
      for (int m = 0; m < 4; ++m) {
        int ch = wch * 64 + m * 16 + l16;
        int slot = (ch * 4 + q) ^ (ch & 7);
        af[m] = *reinterpret_cast<const short8*>(wb + slot * 8);
      }
      #pragma unroll
      for (int n = 0; n < 4; ++n) {
        int row = wrow * 64 + n * 16 + l16;
        int byte = (row * 512 + kb * 64 + q * 16) ^ ((row & 7) << 4);
        bfr[n] = *reinterpret_cast<const short8*>((char*)hbuf + byte);
      }
      #pragma unroll
      for (int m = 0; m < 4; ++m)
        #pragma unroll
        for (int n = 0; n < 4; ++n)
          acc[m][n] = __builtin_amdgcn_mfma_f32_16x16x32_bf16(af[m], bfr[n], acc[m][n], 0, 0, 0);

      __syncthreads();    // DMA(s+1) landed + everyone done reading wbuf[cur]
      cur ^= 1;
    }

    if (L < 2) {
      // epilogue: h_next[row][ch] = relu(acc+bias) -> swizzled hbuf, in place
      #pragma unroll
      for (int m = 0; m < 4; ++m) {
        f32x4 bv = *reinterpret_cast<const f32x4*>(bb + wch * 64 + m * 16 + q * 4);
        int ch = wch * 64 + m * 16 + q * 4;
        #pragma unroll
        for (int n = 0; n < 4; ++n) {
          int row = wrow * 64 + n * 16 + l16;
          f32x4 t = acc[m][n];
          unsigned lo = (unsigned)bfbits(fmaxf(t[0] + bv[0], 0.f))
                      | ((unsigned)bfbits(fmaxf(t[1] + bv[1], 0.f)) << 16);
          unsigned hi = (unsigned)bfbits(fmaxf(t[2] + bv[2], 0.f))
                      | ((unsigned)bfbits(fmaxf(t[3] + bv[3], 0.f)) << 16);
          int byte = (row * 512 + ch * 2) ^ ((row & 7) << 4);
          uint2 pk; pk.x = lo; pk.y = hi;
          *reinterpret_cast<uint2*>((char*)hbuf + byte) = pk;
        }
      }
      __syncthreads();    // h_next visible before next layer's reads
    } else {
      // final layer: relu+bias, sum this wave's 64 rows; combine row halves via
      // pbuf aliasing wbuf (DMA stream ended at step 23).
      float* pbuf = (float*)wbuf;    // [2][256]
      #pragma unroll
      for (int m = 0; m < 4; ++m) {
        f32x4 bv = *reinterpret_cast<const f32x4*>(bb + wch * 64 + m * 16 + q * 4);
        f32x4 s = f32x4{0.f, 0.f, 0.f, 0.f};
        #pragma unroll
        for (int n = 0; n < 4; ++n) {
          s[0] += fmaxf(acc[m][n][0] + bv[0], 0.f);
          s[1] += fmaxf(acc[m][n][1] + bv[1], 0.f);
          s[2] += fmaxf(acc[m][n][2] + bv[2], 0.f);
          s[3] += fmaxf(acc[m][n][3] + bv[3], 0.f);
        }
        #pragma unroll
        for (int r = 0; r < 4; ++r) {
          float x = s[r];
          x += __shfl_xor(x, 1);
          x += __shfl_xor(x, 2);
          x += __shfl_xor(x, 4);
          x += __shfl_xor(x, 8);
          s[r] = x;
        }
        if (l16 == 0) {
          float4 o; o.x = s[0]; o.y = s[1]; o.z = s[2]; o.w = s[3];
          *reinterpret_cast<float4*>(pbuf + wrow * 256 + wch * 64 + m * 16 + q * 4) = o;
        }
      }
      __syncthreads();
      if (tid < 256)
        partial[(size_t)wg * SZ + tid] = pbuf[tid] + pbuf[256 + tid];
    }
  }
  #undef GLOAD
}

// ---------------- final reduction over a: 128 slices per batch ----------------
__global__ void reduce_partials(const float* __restrict__ partial, float* __restrict__ out) {
  int b = blockIdx.x;            // 16 blocks x 256 threads
  int s = threadIdx.x;
  const float* p = partial + (size_t)b * NUMV * SZ + s;
  float acc = 0.f;
  for (int i = 0; i < NUMV; ++i) acc += p[(size_t)i * SZ];
  out[b * SZ + s] = acc;
}

extern "C" void kernel_launch(void* const* d_in, const int* in_sizes, int n_in,
                              void* d_out, int out_size, void* d_ws, size_t ws_size,
                              hipStream_t stream) {
  const float* in_ = (const float*)d_in[0];
  const float* W1  = (const float*)d_in[1];
  const float* b1  = (const float*)d_in[2];
  const float* W2  = (const float*)d_in[3];
  const float* b2  = (const float*)d_in[4];
  const float* W3  = (const float*)d_in[5];
  const float* b3  = (const float*)d_in[6];
  const float* W4  = (const float*)d_in[7];
  const float* b4  = (const float*)d_in[8];
  float* out = (float*)d_out;

  char* ws = (char*)d_ws;
  float* u       = (float*)(ws);                                 // 2 MB
  float* v       = (float*)(ws + (2u << 20));                    // 2 MB
  short* wlay    = (short*)(ws + (4u << 20));                    // 384 KB
  float* partial = (float*)(ws + (4u << 20) + (1u << 19));       // 2 MB

  uv_prep<<<MBATCH * NUMV, 256, 0, stream>>>(in_, W1, b1, u, v);
  w_prep<<<24, 256, 0, stream>>>(W2, W3, W4, wlay);
  fused_mlp<<<MBATCH * NUMV, 512, 0, stream>>>(u, v, wlay, b2, b3, b4, partial);
  reduce_partials<<<MBATCH, 256, 0, stream>>>(partial, out);
}

// Round 15
// 154.026 us; speedup vs baseline: 1.0875x; 1.0875x over previous
//
#include <hip/hip_runtime.h>
#include <hip/hip_bf16.h>

using short8 = __attribute__((ext_vector_type(8))) short;
using f32x4  = __attribute__((ext_vector_type(4))) float;

#define MBATCH 16
#define NUMV   128
#define LEN    64
#define SZ     256

__device__ __forceinline__ unsigned short bfbits(float x) {
  union { float f; unsigned u; } c; c.f = x;
  return (unsigned short)((c.u + 0x8000u) >> 16);   // round-to-nearest
}

// ---------------- prep 1: u[bn][s], v[bn][s] (layer-1 factorization) ----------------
__global__ void uv_prep(const float* __restrict__ in_, const float* __restrict__ W1,
                        const float* __restrict__ b1,
                        float* __restrict__ u, float* __restrict__ v) {
  int bn = blockIdx.x;
  int n  = bn & (NUMV - 1);
  int s  = threadIdx.x;                // 256 threads
  __shared__ float xs[LEN];
  if (s < LEN) xs[s] = in_[bn * LEN + s];
  __syncthreads();
  float fn = (float)n;
  float uu = fn * W1[64 * SZ + s];
  float vv = fn * W1[129 * SZ + s] + b1[s];
  for (int c = 0; c < LEN; ++c) {
    uu = fmaf(xs[c], W1[c * SZ + s], uu);
    vv = fmaf(xs[c], W1[(65 + c) * SZ + s], vv);
  }
  u[bn * SZ + s] = uu;
  v[bn * SZ + s] = vv;
}

// ---------------- prep 2: W2/W3/W4 -> bf16 A-fragments ----------------
// Step-major: step s = L*8+kb is a 16KB chunk; ch-group wv's 4KB block at +wv*4096,
// m-frags at +m*1024. lane (l16,q): Wt[ch = wv*64+m*16+l16][kb*32 + q*8 + 0..7]
__global__ void w_prep(const float* __restrict__ W2, const float* __restrict__ W3,
                       const float* __restrict__ W4, short* __restrict__ wlay) {
  int L = blockIdx.x >> 3, kb = blockIdx.x & 7;     // 24 blocks
  const float* W = (L == 0) ? W2 : (L == 1) ? W3 : W4;
  int m = threadIdx.x >> 6, lane = threadIdx.x & 63;
  int l16 = lane & 15, q = lane >> 4;
  for (int wv = 0; wv < 4; ++wv) {
    int ch = wv * 64 + m * 16 + l16;
    short8 pk;
    for (int i = 0; i < 8; ++i)
      pk[i] = (short)bfbits(W[(kb * 32 + q * 8 + i) * SZ + ch]);
    int f = ((L * 8 + kb) * 4 + wv) * 4 + m;
    reinterpret_cast<short8*>(wlay)[f * 64 + lane] = pk;
  }
}

// ---------------- main fused kernel ----------------
// One WG per (b, a, jhalf): 64 rows, 256 threads = 4 waves; wave = 64ch x 64rows.
// WHOLE-LAYER weights in registers: aw[8][4] = 128 VGPR. aw[kb] for layer L+1
// reloads right after layer L's step kb consumes it -> 7-step latency cover,
// compiler emits counted vmcnt. K-loop: zero barriers, zero load waits.
// LDS swizzle (row&7)<<6 XORs rows into the kb-bits -> bfr reads 32 distinct
// 16B slots = conflict-free (old (row&7)<<4 folded to 8 slots = 8-way).
// Budget: 64 acc + 128 aw + 16 bfr + ~25 addr ~= 235 <= 256 @ launch_bounds(256,2).
__global__ __launch_bounds__(256, 2) void fused_mlp(
    const float* __restrict__ u, const float* __restrict__ v,
    const short* __restrict__ wlay,
    const float* __restrict__ b2, const float* __restrict__ b3, const float* __restrict__ b4,
    float* __restrict__ partial) {
  __shared__ __align__(16) short hbuf[64 * 256];   // 32 KB, byte = row*512 + (col ^ ((row&7)<<6))

  int wg = blockIdx.x;
  int b = wg >> 8, a = (wg >> 1) & 127, jh = wg & 1;
  int tid = threadIdx.x;
  int wave = tid >> 6, lane = tid & 63;
  int l16 = lane & 15, q = lane >> 4;

  const char* wbase = (const char*)wlay + wave * 4096 + lane * 16;

  short8 aw[8][4];
  // preload ALL of layer 0 (32 x 1KB loads; latency hidden under the h1 phase)
  #pragma unroll
  for (int kb = 0; kb < 8; ++kb)
    #pragma unroll
    for (int m = 0; m < 4; ++m)
      aw[kb][m] = *reinterpret_cast<const short8*>(wbase + kb * 16384 + m * 1024);

  // ---- h1 = relu(u[b,j] + v[b,a]) -> bf16, swizzled row-major in LDS ----
  {
    const float4* ub = (const float4*)(u + (size_t)b * NUMV * SZ) + jh * 64 * 64;
    const float4* vb = (const float4*)(v + ((size_t)b * NUMV + a) * SZ);
    #pragma unroll
    for (int it = 0; it < 16; ++it) {
      int flat = tid + it * 256;          // over 64 rows * 64 col-quads
      int jr = flat >> 6, c4 = flat & 63;
      float4 uu = ub[jr * 64 + c4];
      float4 vv = vb[c4];
      unsigned lo = (unsigned)bfbits(fmaxf(uu.x + vv.x, 0.f))
                  | ((unsigned)bfbits(fmaxf(uu.y + vv.y, 0.f)) << 16);
      unsigned hi = (unsigned)bfbits(fmaxf(uu.z + vv.z, 0.f))
                  | ((unsigned)bfbits(fmaxf(uu.w + vv.w, 0.f)) << 16);
      int byte = jr * 512 + ((c4 * 8) ^ ((jr & 7) << 6));
      uint2 pk; pk.x = lo; pk.y = hi;
      *reinterpret_cast<uint2*>((char*)hbuf + byte) = pk;
    }
  }

  __syncthreads();        // h1 visible to all waves

  #pragma unroll
  for (int L = 0; L < 3; ++L) {
    const float* bb = (L == 0) ? b2 : (L == 1) ? b3 : b4;

    f32x4 acc[4][4];
    #pragma unroll
    for (int m = 0; m < 4; ++m)
      #pragma unroll
      for (int n = 0; n < 4; ++n)
        acc[m][n] = f32x4{0.f, 0.f, 0.f, 0.f};

    #pragma unroll
    for (int kb = 0; kb < 8; ++kb) {
      short8 bfr[4];
      #pragma unroll
      for (int n = 0; n < 4; ++n) {
        int row = n * 16 + l16;
        int byte = row * 512 + ((kb * 64 + q * 16) ^ ((row & 7) << 6));
        bfr[n] = *reinterpret_cast<const short8*>((char*)hbuf + byte);
      }
      #pragma unroll
      for (int m = 0; m < 4; ++m)
        #pragma unroll
        for (int n = 0; n < 4; ++n)
          acc[m][n] = __builtin_amdgcn_mfma_f32_16x16x32_bf16(aw[kb][m], bfr[n], acc[m][n], 0, 0, 0);
      // stagger: reload aw[kb] with layer L+1's fragments (WAR after last use above)
      if (L < 2) {
        #pragma unroll
        for (int m = 0; m < 4; ++m)
          aw[kb][m] = *reinterpret_cast<const short8*>(
              wbase + (L + 1) * 131072 + kb * 16384 + m * 1024);
      }
    }

    __syncthreads();      // all waves done reading hbuf for this layer

    if (L < 2) {
      // epilogue: h_next[row][ch] = relu(acc+bias) -> swizzled hbuf, in place
      #pragma unroll
      for (int m = 0; m < 4; ++m) {
        f32x4 bv = *reinterpret_cast<const f32x4*>(bb + wave * 64 + m * 16 + q * 4);
        int chb = wave * 128 + m * 32 + q * 8;     // ch*2 bytes
        #pragma unroll
        for (int n = 0; n < 4; ++n) {
          int row = n * 16 + l16;
          f32x4 t = acc[m][n];
          unsigned lo = (unsigned)bfbits(fmaxf(t[0] + bv[0], 0.f))
                      | ((unsigned)bfbits(fmaxf(t[1] + bv[1], 0.f)) << 16);
          unsigned hi = (unsigned)bfbits(fmaxf(t[2] + bv[2], 0.f))
                      | ((unsigned)bfbits(fmaxf(t[3] + bv[3], 0.f)) << 16);
          int byte = row * 512 + (chb ^ ((row & 7) << 6));
          uint2 pk; pk.x = lo; pk.y = hi;
          *reinterpret_cast<uint2*>((char*)hbuf + byte) = pk;
        }
      }
      __syncthreads();    // h_next visible before next layer's reads
    } else {
      // final layer: relu+bias, sum this wave's 64 rows, write partial directly
      #pragma unroll
      for (int m = 0; m < 4; ++m) {
        f32x4 bv = *reinterpret_cast<const f32x4*>(bb + wave * 64 + m * 16 + q * 4);
        f32x4 s = f32x4{0.f, 0.f, 0.f, 0.f};
        #pragma unroll
        for (int n = 0; n < 4; ++n) {
          s[0] += fmaxf(acc[m][n][0] + bv[0], 0.f);
          s[1] += fmaxf(acc[m][n][1] + bv[1], 0.f);
          s[2] += fmaxf(acc[m][n][2] + bv[2], 0.f);
          s[3] += fmaxf(acc[m][n][3] + bv[3], 0.f);
        }
        #pragma unroll
        for (int r = 0; r < 4; ++r) {
          float x = s[r];
          x += __shfl_xor(x, 1);
          x += __shfl_xor(x, 2);
          x += __shfl_xor(x, 4);
          x += __shfl_xor(x, 8);
          s[r] = x;
        }
        if (l16 == 0) {
          float4 o; o.x = s[0]; o.y = s[1]; o.z = s[2]; o.w = s[3];
          *reinterpret_cast<float4*>(partial + (size_t)wg * SZ + wave * 64 + m * 16 + q * 4) = o;
        }
      }
    }
  }
}

// ---------------- final reduction over (a, jhalf): 256 slices per batch ----------------
__global__ void reduce_partials(const float* __restrict__ partial, float* __restrict__ out) {
  int b = blockIdx.x;            // 16 blocks x 256 threads
  int s = threadIdx.x;
  const float* p = partial + (size_t)b * 256 * SZ + s;
  float acc = 0.f;
  for (int i = 0; i < 256; ++i) acc += p[(size_t)i * SZ];
  out[b * SZ + s] = acc;
}

extern "C" void kernel_launch(void* const* d_in, const int* in_sizes, int n_in,
                              void* d_out, int out_size, void* d_ws, size_t ws_size,
                              hipStream_t stream) {
  const float* in_ = (const float*)d_in[0];
  const float* W1  = (const float*)d_in[1];
  const float* b1  = (const float*)d_in[2];
  const float* W2  = (const float*)d_in[3];
  const float* b2  = (const float*)d_in[4];
  const float* W3  = (const float*)d_in[5];
  const float* b3  = (const float*)d_in[6];
  const float* W4  = (const float*)d_in[7];
  const float* b4  = (const float*)d_in[8];
  float* out = (float*)d_out;

  char* ws = (char*)d_ws;
  float* u       = (float*)(ws);                                 // 2 MB
  float* v       = (float*)(ws + (2u << 20));                    // 2 MB
  short* wlay    = (short*)(ws + (4u << 20));                    // 384 KB
  float* partial = (float*)(ws + (4u << 20) + (1u << 19));       // 4 MB

  uv_prep<<<MBATCH * NUMV, 256, 0, stream>>>(in_, W1, b1, u, v);
  w_prep<<<24, 256, 0, stream>>>(W2, W3, W4, wlay);
  fused_mlp<<<MBATCH * NUMV * 2, 256, 0, stream>>>(u, v, wlay, b2, b3, b4, partial);
  reduce_partials<<<MBATCH, 256, 0, stream>>>(partial, out);
}

// Round 16
// 136.550 us; speedup vs baseline: 1.2267x; 1.1280x over previous
//
#include <hip/hip_runtime.h>
#include <hip/hip_bf16.h>

using short8 = __attribute__((ext_vector_type(8))) short;
using f32x4  = __attribute__((ext_vector_type(4))) float;

#define MBATCH 16
#define NUMV   128
#define LEN    64
#define SZ     256

__device__ __forceinline__ unsigned short bfbits(float x) {
  union { float f; unsigned u; } c; c.f = x;
  return (unsigned short)((c.u + 0x8000u) >> 16);   // round-to-nearest
}

// ---------------- prep 1: u[bn][s], v[bn][s] (layer-1 factorization) ----------------
__global__ void uv_prep(const float* __restrict__ in_, const float* __restrict__ W1,
                        const float* __restrict__ b1,
                        float* __restrict__ u, float* __restrict__ v) {
  int bn = blockIdx.x;
  int n  = bn & (NUMV - 1);
  int s  = threadIdx.x;                // 256 threads
  __shared__ float xs[LEN];
  if (s < LEN) xs[s] = in_[bn * LEN + s];
  __syncthreads();
  float fn = (float)n;
  float uu = fn * W1[64 * SZ + s];
  float vv = fn * W1[129 * SZ + s] + b1[s];
  for (int c = 0; c < LEN; ++c) {
    uu = fmaf(xs[c], W1[c * SZ + s], uu);
    vv = fmaf(xs[c], W1[(65 + c) * SZ + s], vv);
  }
  u[bn * SZ + s] = uu;
  v[bn * SZ + s] = vv;
}

// ---------------- prep 2: W2/W3/W4 -> bf16 A-fragments ----------------
// Step-major 16KB chunks (s = L*8+kb); ch-half wch's 8KB block at +wch*8192,
// m-frags (m=0..7) at +m*1024. lane (l16,q): Wt[ch = wch*128+m*16+l16][kb*32+q*8+0..7]
__global__ void w_prep(const float* __restrict__ W2, const float* __restrict__ W3,
                       const float* __restrict__ W4, short* __restrict__ wlay) {
  int L = blockIdx.x >> 3, kb = blockIdx.x & 7;     // 24 blocks
  const float* W = (L == 0) ? W2 : (L == 1) ? W3 : W4;
  int mq = threadIdx.x >> 6, lane = threadIdx.x & 63;
  int l16 = lane & 15, q = lane >> 4;
  for (int wv = 0; wv < 4; ++wv) {
    int wch = wv >> 1, mhi = wv & 1;
    int m = mhi * 4 + mq;                           // 0..7
    int ch = wch * 128 + m * 16 + l16;
    short8 pk;
    for (int i = 0; i < 8; ++i)
      pk[i] = (short)bfbits(W[(kb * 32 + q * 8 + i) * SZ + ch]);
    size_t byteoff = (size_t)(L * 8 + kb) * 16384 + wch * 8192 + m * 1024 + lane * 16;
    *reinterpret_cast<short8*>((char*)wlay + byteoff) = pk;
  }
}

// ---------------- main fused kernel ----------------
// One WG per (b, a): 128 rows, 256 threads = 4 waves.
// FAT wave tile 128ch x 64rows: acc[8][4] = 128 AGPR, 32 MFMA per kb-step ->
// HALF the step count of the 64ch tile (192 vs 384 steps/SIMD) at similar per-step
// latency. awA/awB 2-deep ping-pong (64 VGPR). Total ~225 regs < 256 @ (256,2):
// no spill, 2 waves/SIMD, 2 WGs/CU. ZERO barriers in K-loop. LDS = 64KB hbuf.
__global__ __launch_bounds__(256, 2) void fused_mlp(
    const float* __restrict__ u, const float* __restrict__ v,
    const short* __restrict__ wlay,
    const float* __restrict__ b2, const float* __restrict__ b3, const float* __restrict__ b4,
    float* __restrict__ partial) {
  __shared__ __align__(16) short hbuf[128 * 256];   // 64 KB, byte ^= (row&7)<<4

  int wg = blockIdx.x;
  int b = wg >> 7, a = wg & 127;
  int tid = threadIdx.x;
  int wave = tid >> 6, lane = tid & 63;
  int wch = wave & 1, wrow = wave >> 1;
  int l16 = lane & 15, q = lane >> 4;

  const char* wptr = (const char*)wlay + wch * 8192 + lane * 16;  // step-0, per-lane

  short8 awA[8], awB[8];
  // preload step-0 fragments (latency hidden under h1 phase)
  #pragma unroll
  for (int m = 0; m < 8; ++m)
    awA[m] = *reinterpret_cast<const short8*>(wptr + m * 1024);

  // ---- h1 = relu(u[b,j] + v[b,a]) -> bf16, swizzled row-major in LDS ----
  {
    const float4* ub = (const float4*)(u + (size_t)b * NUMV * SZ);
    const float4* vb = (const float4*)(v + ((size_t)b * NUMV + a) * SZ);
    #pragma unroll
    for (int it = 0; it < 32; ++it) {
      int flat = tid + it * 256;          // over 128 rows * 64 col-quads
      int jr = flat >> 6, c4 = flat & 63;
      float4 uu = ub[jr * 64 + c4];
      float4 vv = vb[c4];
      unsigned lo = (unsigned)bfbits(fmaxf(uu.x + vv.x, 0.f))
                  | ((unsigned)bfbits(fmaxf(uu.y + vv.y, 0.f)) << 16);
      unsigned hi = (unsigned)bfbits(fmaxf(uu.z + vv.z, 0.f))
                  | ((unsigned)bfbits(fmaxf(uu.w + vv.w, 0.f)) << 16);
      int byte = (jr * 512 + c4 * 8) ^ ((jr & 7) << 4);
      uint2 pk; pk.x = lo; pk.y = hi;
      *reinterpret_cast<uint2*>((char*)hbuf + byte) = pk;
    }
  }

  __syncthreads();        // h1 visible to all waves

  #pragma unroll
  for (int L = 0; L < 3; ++L) {
    const float* bb = (L == 0) ? b2 : (L == 1) ? b3 : b4;

    f32x4 acc[8][4];
    #pragma unroll
    for (int m = 0; m < 8; ++m)
      #pragma unroll
      for (int n = 0; n < 4; ++n)
        acc[m][n] = f32x4{0.f, 0.f, 0.f, 0.f};

    #pragma unroll
    for (int kb = 0; kb < 8; ++kb) {
      // prefetch step s+1 into the other bank, issued BEFORE this step's MFMAs
      if (L * 8 + kb < 23) {
        if ((kb & 1) == 0) {
          #pragma unroll
          for (int m = 0; m < 8; ++m)
            awB[m] = *reinterpret_cast<const short8*>(wptr + 16384 + m * 1024);
        } else {
          #pragma unroll
          for (int m = 0; m < 8; ++m)
            awA[m] = *reinterpret_cast<const short8*>(wptr + 16384 + m * 1024);
        }
      }
      wptr += 16384;

      short8 bfr[4];
      #pragma unroll
      for (int n = 0; n < 4; ++n) {
        int row = wrow * 64 + n * 16 + l16;
        int byte = (row * 512 + kb * 64 + q * 16) ^ ((row & 7) << 4);
        bfr[n] = *reinterpret_cast<const short8*>((char*)hbuf + byte);
      }
      if ((kb & 1) == 0) {
        #pragma unroll
        for (int m = 0; m < 8; ++m)
          #pragma unroll
          for (int n = 0; n < 4; ++n)
            acc[m][n] = __builtin_amdgcn_mfma_f32_16x16x32_bf16(awA[m], bfr[n], acc[m][n], 0, 0, 0);
      } else {
        #pragma unroll
        for (int m = 0; m < 8; ++m)
          #pragma unroll
          for (int n = 0; n < 4; ++n)
            acc[m][n] = __builtin_amdgcn_mfma_f32_16x16x32_bf16(awB[m], bfr[n], acc[m][n], 0, 0, 0);
      }
    }

    __syncthreads();      // all waves done reading hbuf for this layer

    if (L < 2) {
      // epilogue: h_next[row][ch] = relu(acc+bias) -> swizzled hbuf, in place
      #pragma unroll
      for (int m = 0; m < 8; ++m) {
        int ch = wch * 128 + m * 16 + q * 4;
        f32x4 bv = *reinterpret_cast<const f32x4*>(bb + ch);
        #pragma unroll
        for (int n = 0; n < 4; ++n) {
          int row = wrow * 64 + n * 16 + l16;
          f32x4 t = acc[m][n];
          unsigned lo = (unsigned)bfbits(fmaxf(t[0] + bv[0], 0.f))
                      | ((unsigned)bfbits(fmaxf(t[1] + bv[1], 0.f)) << 16);
          unsigned hi = (unsigned)bfbits(fmaxf(t[2] + bv[2], 0.f))
                      | ((unsigned)bfbits(fmaxf(t[3] + bv[3], 0.f)) << 16);
          int byte = (row * 512 + ch * 2) ^ ((row & 7) << 4);
          uint2 pk; pk.x = lo; pk.y = hi;
          *reinterpret_cast<uint2*>((char*)hbuf + byte) = pk;
        }
      }
      __syncthreads();    // h_next visible before next layer's reads
    } else {
      // final layer: relu+bias, sum this wave's 64 rows; combine row halves via
      // pbuf aliasing hbuf (dead after the sync above).
      float* pbuf = (float*)hbuf;    // [2][256]
      #pragma unroll
      for (int m = 0; m < 8; ++m) {
        int ch = wch * 128 + m * 16 + q * 4;
        f32x4 bv = *reinterpret_cast<const f32x4*>(bb + ch);
        f32x4 s = f32x4{0.f, 0.f, 0.f, 0.f};
        #pragma unroll
        for (int n = 0; n < 4; ++n) {
          s[0] += fmaxf(acc[m][n][0] + bv[0], 0.f);
          s[1] += fmaxf(acc[m][n][1] + bv[1], 0.f);
          s[2] += fmaxf(acc[m][n][2] + bv[2], 0.f);
          s[3] += fmaxf(acc[m][n][3] + bv[3], 0.f);
        }
        #pragma unroll
        for (int r = 0; r < 4; ++r) {
          float x = s[r];
          x += __shfl_xor(x, 1);
          x += __shfl_xor(x, 2);
          x += __shfl_xor(x, 4);
          x += __shfl_xor(x, 8);
          s[r] = x;
        }
        if (l16 == 0) {
          float4 o; o.x = s[0]; o.y = s[1]; o.z = s[2]; o.w = s[3];
          *reinterpret_cast<float4*>(pbuf + wrow * 256 + ch) = o;
        }
      }
      __syncthreads();
      if (tid < 256)
        partial[(size_t)wg * SZ + tid] = pbuf[tid] + pbuf[256 + tid];
    }
  }
}

// ---------------- final reduction over a: 128 slices per batch ----------------
__global__ void reduce_partials(const float* __restrict__ partial, float* __restrict__ out) {
  int b = blockIdx.x;            // 16 blocks x 256 threads
  int s = threadIdx.x;
  const float* p = partial + (size_t)b * NUMV * SZ + s;
  float acc = 0.f;
  for (int i = 0; i < NUMV; ++i) acc += p[(size_t)i * SZ];
  out[b * SZ + s] = acc;
}

extern "C" void kernel_launch(void* const* d_in, const int* in_sizes, int n_in,
                              void* d_out, int out_size, void* d_ws, size_t ws_size,
                              hipStream_t stream) {
  const float* in_ = (const float*)d_in[0];
  const float* W1  = (const float*)d_in[1];
  const float* b1  = (const float*)d_in[2];
  const float* W2  = (const float*)d_in[3];
  const float* b2  = (const float*)d_in[4];
  const float* W3  = (const float*)d_in[5];
  const float* b3  = (const float*)d_in[6];
  const float* W4  = (const float*)d_in[7];
  const float* b4  = (const float*)d_in[8];
  float* out = (float*)d_out;

  char* ws = (char*)d_ws;
  float* u       = (float*)(ws);                                 // 2 MB
  float* v       = (float*)(ws + (2u << 20));                    // 2 MB
  short* wlay    = (short*)(ws + (4u << 20));                    // 384 KB
  float* partial = (float*)(ws + (4u << 20) + (1u << 19));       // 2 MB

  uv_prep<<<MBATCH * NUMV, 256, 0, stream>>>(in_, W1, b1, u, v);
  w_prep<<<24, 256, 0, stream>>>(W2, W3, W4, wlay);
  fused_mlp<<<MBATCH * NUMV, 256, 0, stream>>>(u, v, wlay, b2, b3, b4, partial);
  reduce_partials<<<MBATCH, 256, 0, stream>>>(partial, out);
}